// Round 7
// baseline (259.087 us; speedup 1.0000x reference)
//
#include <hip/hip_runtime.h>
#include <hip/hip_bf16.h>
#include <math.h>

#define B_   2048
#define K_   256
#define AD_  512
#define IN_  768
#define NR_  500
#define NRP_ 512   // padded
#define NE_  100000

typedef __attribute__((ext_vector_type(8))) short short8;
typedef __attribute__((ext_vector_type(4))) float float4v;

__device__ __forceinline__ unsigned short f2bf(float f) {
    unsigned int u = __float_as_uint(f);
    unsigned int r = u + 0x7FFF + ((u >> 16) & 1);   // round-to-nearest-even
    return (unsigned short)(r >> 16);
}
__device__ __forceinline__ float bf2f(short s) {
    return __uint_as_float(((unsigned int)(unsigned short)s) << 16);
}

// one prep kernel: emb_e->bf16 (bulk), cast concat [E|H|Q] -> Xb, W1/W2/emb_r -> bf16
#define EE_N4 (NE_ * 256 / 4)    // 6,400,000
#define X_N4  (B_ * IN_ / 4)     // 393,216
#define W1_N4 (AD_ * IN_ / 4)    // 98,304
#define W2_N4 (AD_ * AD_ / 4)    // 65,536
#define ER_N4 (NR_ * 256 / 4)    // 32,000
#define PREP_TOTAL (EE_N4 + X_N4 + W1_N4 + W2_N4 + ER_N4)
__global__ __launch_bounds__(256) void prep_kernel(
    const float* __restrict__ E, const float* __restrict__ H,
    const float* __restrict__ Q, const float* __restrict__ W1,
    const float* __restrict__ W2, const float* __restrict__ emb_r,
    const float* __restrict__ emb_e,
    ushort* __restrict__ Xb, ushort* __restrict__ W1b,
    ushort* __restrict__ W2b, ushort* __restrict__ emb_rb,
    ushort* __restrict__ emb_eb)
{
    int t = blockIdx.x * 256 + threadIdx.x;
    const float* src; ushort* dst; long off;
    if (t < EE_N4) { src = emb_e; dst = emb_eb; off = t; }
    else {
        t -= EE_N4;
        if (t < X_N4) {
            const int base = t * 4;
            const int row = base / IN_, col = base % IN_;
            src = (col < 256) ? &E[row * 256 + col]
                : (col < 512) ? &H[row * 256 + col - 256]
                              : &Q[row * 256 + col - 512];
            const float4 v = *(const float4*)src;
            ushort4 o;
            o.x = f2bf(v.x); o.y = f2bf(v.y); o.z = f2bf(v.z); o.w = f2bf(v.w);
            *(ushort4*)&Xb[base] = o;
            return;
        }
        t -= X_N4;
        if (t < W1_N4)                 { src = W1;    dst = W1b;    off = t; }
        else if (t < W1_N4 + W2_N4)    { src = W2;    dst = W2b;    off = t - W1_N4; }
        else if (t < W1_N4 + W2_N4 + ER_N4) { src = emb_r; dst = emb_rb; off = t - W1_N4 - W2_N4; }
        else return;
    }
    const float4 v = *(const float4*)&src[off * 4];
    ushort4 o;
    o.x = f2bf(v.x); o.y = f2bf(v.y); o.z = f2bf(v.z); o.w = f2bf(v.w);
    *(ushort4*)&dst[off * 4] = o;
}

// bf16 MFMA GEMM, BK=64, double-buffered LDS (one barrier per k-step).
// C[m][n] = act(sum_k A[m][k]*Bw[n][k] + bias[n]); A [M][K], Bw [N][K] row-major bf16.
// Tile 64x64, 4 waves; output stride fixed = 512.
template<int K, bool RELU, bool OUT_BF16, bool BIAS, bool EMIT_RHALF>
__global__ __launch_bounds__(256) void gemm_bf16_kernel(
    const ushort* __restrict__ A, const ushort* __restrict__ Bw,
    const float* __restrict__ bias, ushort* __restrict__ outb,
    float* __restrict__ outf, ushort* __restrict__ rhalf)
{
    constexpr int PITCH = 72;                     // 64 + 8 pad (ushort units)
    __shared__ ushort Asl[2][64 * PITCH];
    __shared__ ushort Bsl[2][64 * PITCH];
    const int tid = threadIdx.x;
    const int lane = tid & 63, w = tid >> 6;
    const int n0 = blockIdx.x * 64, m0 = blockIdx.y * 64;
    const int lrow = tid >> 2, lcg = (tid & 3) * 16;  // 4 loaders/row x 32B
    const int q = lane >> 4, l16 = lane & 15;

    const ushort* aptr = &A[(size_t)(m0 + lrow) * K + lcg];
    const ushort* bptr = &Bw[(size_t)(n0 + lrow) * K + lcg];

    short8 ra0 = *(const short8*)aptr;
    short8 ra1 = *(const short8*)(aptr + 8);
    short8 rb0 = *(const short8*)bptr;
    short8 rb1 = *(const short8*)(bptr + 8);
    *(short8*)&Asl[0][lrow * PITCH + lcg]     = ra0;
    *(short8*)&Asl[0][lrow * PITCH + lcg + 8] = ra1;
    *(short8*)&Bsl[0][lrow * PITCH + lcg]     = rb0;
    *(short8*)&Bsl[0][lrow * PITCH + lcg + 8] = rb1;

    float4v acc[4] = {};
    int buf = 0;
    __syncthreads();
    for (int k0 = 0; k0 < K; k0 += 64) {
        if (k0 + 64 < K) {                        // prefetch next tile into regs
            ra0 = *(const short8*)(aptr + k0 + 64);
            ra1 = *(const short8*)(aptr + k0 + 64 + 8);
            rb0 = *(const short8*)(bptr + k0 + 64);
            rb1 = *(const short8*)(bptr + k0 + 64 + 8);
        }
        #pragma unroll
        for (int kh = 0; kh < 64; kh += 32) {
            const short8 af = *(const short8*)&Asl[buf][(w * 16 + l16) * PITCH + kh + q * 8];
            #pragma unroll
            for (int jn = 0; jn < 4; ++jn) {
                const short8 bfr = *(const short8*)&Bsl[buf][(jn * 16 + l16) * PITCH + kh + q * 8];
                acc[jn] = __builtin_amdgcn_mfma_f32_16x16x32_bf16(af, bfr, acc[jn], 0, 0, 0);
            }
        }
        if (k0 + 64 < K) {
            *(short8*)&Asl[buf ^ 1][lrow * PITCH + lcg]     = ra0;
            *(short8*)&Asl[buf ^ 1][lrow * PITCH + lcg + 8] = ra1;
            *(short8*)&Bsl[buf ^ 1][lrow * PITCH + lcg]     = rb0;
            *(short8*)&Bsl[buf ^ 1][lrow * PITCH + lcg + 8] = rb1;
            __syncthreads();
            buf ^= 1;
        }
    }
    #pragma unroll
    for (int jn = 0; jn < 4; ++jn) {
        const int n = n0 + jn * 16 + l16;
        const float bn = BIAS ? bias[n] : 0.0f;
        #pragma unroll
        for (int r = 0; r < 4; ++r) {
            const int m = m0 + w * 16 + q * 4 + r;
            float c = acc[jn][r] + bn;
            if (RELU) c = fmaxf(c, 0.0f);
            if (OUT_BF16) outb[(size_t)m * AD_ + n] = f2bf(c);
            else if (!EMIT_RHALF || n >= 256) outf[(size_t)m * AD_ + n] = c;
            if (EMIT_RHALF && n < 256) rhalf[(size_t)m * 256 + n] = f2bf(c);
        }
    }
}

// scores + masked softmax + entropy. One block per batch row, 4 waves.
// emb_r part precomputed in R[b][r]; emb_e gathered as bf16, TWO rows per
// wave-load (lanes 0-31 row k, 32-63 row k+1), width-32 reduce.
// Masked-out rows (mask==0) are SKIPPED: their softmax weight is exp(-1e31)=0,
// so the gather is dead work; predication is half-wave-uniform (all 32 lanes
// share the row) so the exec-masked load never fetches those lines.
__global__ __launch_bounds__(256) void scores_kernel(
    const float* __restrict__ X2, const float* __restrict__ R,
    const ushort* __restrict__ emb_eb, const float* __restrict__ mask,
    const int* __restrict__ r_space, const int* __restrict__ e_space,
    float* __restrict__ dist, float* __restrict__ entropy)
{
    const int b = blockIdx.x;
    const int tid = threadIdx.x;
    const int lane = tid & 63, wid = tid >> 6;
    const int half = lane >> 5, l32 = lane & 31;

    __shared__ int   s_e[K_];
    __shared__ int   s_v[K_];
    __shared__ float s_dot[K_];
    __shared__ float s_red[12];

    // phase A: fully parallel per-thread (k == tid) bias precompute
    s_e[tid] = e_space[b * K_ + tid];
    const int   r_mine = r_space[b * K_ + tid];
    const float mk     = mask[b * K_ + tid];
    s_v[tid] = (mk != 0.0f);
    const float bias   = R[(size_t)b * NRP_ + r_mine] - (1.0f - mk) * 1e31f;
    const float4 x0 = *(const float4*)&X2[(size_t)b * AD_ + 256 + l32 * 8];
    const float4 x1 = *(const float4*)&X2[(size_t)b * AD_ + 256 + l32 * 8 + 4];
    __syncthreads();

    // phase B: wave wid handles k in [wid*64, wid*64+64); up to 8 loads (16 rows) in flight
    const int kbase = wid * 64;
    #pragma unroll
    for (int kk = 0; kk < 64; kk += 16) {
        float p[8];
        #pragma unroll
        for (int u = 0; u < 8; ++u) {
            const int row = kbase + kk + u * 2 + half;
            p[u] = 0.0f;
            if (s_v[row]) {                       // half-wave-uniform predicate
                const int e = s_e[row];
                const short8 ae = __builtin_nontemporal_load(
                    (const short8*)&emb_eb[(size_t)e * 256 + l32 * 8]);
                p[u] = bf2f(ae[0]) * x0.x + bf2f(ae[1]) * x0.y
                     + bf2f(ae[2]) * x0.z + bf2f(ae[3]) * x0.w
                     + bf2f(ae[4]) * x1.x + bf2f(ae[5]) * x1.y
                     + bf2f(ae[6]) * x1.z + bf2f(ae[7]) * x1.w;
            }
        }
        #pragma unroll
        for (int off = 16; off >= 1; off >>= 1) {
            #pragma unroll
            for (int u = 0; u < 8; ++u) p[u] += __shfl_down(p[u], off, 32);
        }
        if (l32 == 0) {
            #pragma unroll
            for (int u = 0; u < 8; ++u) s_dot[kbase + kk + u * 2 + half] = p[u];
        }
    }
    __syncthreads();

    const float v = s_dot[tid] + bias;

    // block max
    float m = v;
    #pragma unroll
    for (int off = 32; off >= 1; off >>= 1) m = fmaxf(m, __shfl_down(m, off));
    if (lane == 0) s_red[wid] = m;
    __syncthreads();
    if (tid == 0)
        s_red[8] = fmaxf(fmaxf(s_red[0], s_red[1]), fmaxf(s_red[2], s_red[3]));
    __syncthreads();
    const float bmax = s_red[8];

    // joint block sum of ev and ev*(v-bmax)
    const float ev = __expf(v - bmax);       // masked: exp(-1e31)=0
    float s = ev;
    float t = ev * (v - bmax);               // masked: 0 * finite = 0
    #pragma unroll
    for (int off = 32; off >= 1; off >>= 1) {
        s += __shfl_down(s, off);
        t += __shfl_down(t, off);
    }
    if (lane == 0) { s_red[wid] = s; s_red[4 + wid] = t; }
    __syncthreads();
    if (tid == 0) {
        s_red[9]  = s_red[0] + s_red[1] + s_red[2] + s_red[3];
        s_red[10] = s_red[4] + s_red[5] + s_red[6] + s_red[7];
    }
    __syncthreads();
    const float ssum = s_red[9];

    dist[(size_t)b * K_ + tid] = ev / ssum;
    if (tid == 0)
        entropy[b] = logf(ssum) - s_red[10] / ssum;   // = -sum p log p
}

extern "C" void kernel_launch(void* const* d_in, const int* in_sizes, int n_in,
                              void* d_out, int out_size, void* d_ws, size_t ws_size,
                              hipStream_t stream) {
    const float* E     = (const float*)d_in[0];
    const float* H     = (const float*)d_in[1];
    const float* Q     = (const float*)d_in[2];
    const float* W1    = (const float*)d_in[3];
    const float* b1    = (const float*)d_in[4];
    const float* W2    = (const float*)d_in[5];
    const float* b2    = (const float*)d_in[6];
    const float* emb_r = (const float*)d_in[7];
    const float* emb_e = (const float*)d_in[8];
    const float* mask  = (const float*)d_in[9];
    const int* r_space = (const int*)d_in[10];
    const int* e_space = (const int*)d_in[11];

    float* out_dist = (float*)d_out;
    float* out_ent  = out_dist + (size_t)B_ * K_;

    char* ws = (char*)d_ws;
    ushort* Xb     = (ushort*)ws;  ws += (size_t)B_ * IN_ * 2;     //  3.00 MB
    ushort* W1b    = (ushort*)ws;  ws += (size_t)AD_ * IN_ * 2;    //  0.75 MB
    ushort* W2b    = (ushort*)ws;  ws += (size_t)AD_ * AD_ * 2;    //  0.50 MB
    ushort* emb_rb = (ushort*)ws;  ws += (size_t)NRP_ * 256 * 2;   //  0.25 MB (rows 500-511 poison, unread)
    ushort* emb_eb = (ushort*)ws;  ws += (size_t)NE_ * 256 * 2;    // 51.20 MB
    ushort* H1b    = (ushort*)ws;  ws += (size_t)B_ * AD_ * 2;     //  2.00 MB
    float*  X2     = (float*)ws;   ws += (size_t)B_ * AD_ * 4;     //  4.00 MB (n<256 left poisoned, unread)
    ushort* X2rb   = (ushort*)ws;  ws += (size_t)B_ * 256 * 2;     //  1.00 MB
    float*  Rt     = (float*)ws;   ws += (size_t)B_ * NRP_ * 4;    //  4.00 MB

    prep_kernel<<<(PREP_TOTAL + 255) / 256, 256, 0, stream>>>(
        E, H, Q, W1, W2, emb_r, emb_e, Xb, W1b, W2b, emb_rb, emb_eb);

    dim3 g(AD_ / 64, B_ / 64);   // (8, 32)
    gemm_bf16_kernel<IN_, true,  true,  true,  false><<<g, 256, 0, stream>>>(
        Xb, W1b, b1, H1b, nullptr, nullptr);
    gemm_bf16_kernel<AD_, false, false, true,  true ><<<g, 256, 0, stream>>>(
        H1b, W2b, b2, nullptr, X2, X2rb);
    // R = X2[:, :256] @ emb_r^T  -> [B, 512pad] f32
    gemm_bf16_kernel<256, false, false, false, false><<<dim3(NRP_ / 64, B_ / 64), 256, 0, stream>>>(
        X2rb, emb_rb, nullptr, nullptr, Rt, nullptr);

    scores_kernel<<<B_, 256, 0, stream>>>(X2, Rt, emb_eb, mask,
                                          r_space, e_space, out_dist, out_ent);
}

// Round 8
// 237.473 us; speedup vs baseline: 1.0910x; 1.0910x over previous
//
#include <hip/hip_runtime.h>
#include <hip/hip_bf16.h>
#include <math.h>

#define B_   2048
#define K_   256
#define AD_  512
#define IN_  768
#define NR_  500
#define NRP_ 512   // padded
#define NE_  100000

typedef __attribute__((ext_vector_type(8))) short short8;
typedef __attribute__((ext_vector_type(4))) float float4v;

__device__ __forceinline__ unsigned short f2bf(float f) {
    unsigned int u = __float_as_uint(f);
    unsigned int r = u + 0x7FFF + ((u >> 16) & 1);   // round-to-nearest-even
    return (unsigned short)(r >> 16);
}
__device__ __forceinline__ float bf2f(short s) {
    return __uint_as_float(((unsigned int)(unsigned short)s) << 16);
}

// one prep kernel: emb_e->bf16 (bulk), cast concat [E|H|Q] -> Xb, W1/W2/emb_r -> bf16
#define EE_N4 (NE_ * 256 / 4)    // 6,400,000
#define X_N4  (B_ * IN_ / 4)     // 393,216
#define W1_N4 (AD_ * IN_ / 4)    // 98,304
#define W2_N4 (AD_ * AD_ / 4)    // 65,536
#define ER_N4 (NR_ * 256 / 4)    // 32,000
#define PREP_TOTAL (EE_N4 + X_N4 + W1_N4 + W2_N4 + ER_N4)
__global__ __launch_bounds__(256) void prep_kernel(
    const float* __restrict__ E, const float* __restrict__ H,
    const float* __restrict__ Q, const float* __restrict__ W1,
    const float* __restrict__ W2, const float* __restrict__ emb_r,
    const float* __restrict__ emb_e,
    ushort* __restrict__ Xb, ushort* __restrict__ W1b,
    ushort* __restrict__ W2b, ushort* __restrict__ emb_rb,
    ushort* __restrict__ emb_eb)
{
    int t = blockIdx.x * 256 + threadIdx.x;
    const float* src; ushort* dst; long off;
    if (t < EE_N4) { src = emb_e; dst = emb_eb; off = t; }
    else {
        t -= EE_N4;
        if (t < X_N4) {
            const int base = t * 4;
            const int row = base / IN_, col = base % IN_;
            src = (col < 256) ? &E[row * 256 + col]
                : (col < 512) ? &H[row * 256 + col - 256]
                              : &Q[row * 256 + col - 512];
            const float4 v = *(const float4*)src;
            ushort4 o;
            o.x = f2bf(v.x); o.y = f2bf(v.y); o.z = f2bf(v.z); o.w = f2bf(v.w);
            *(ushort4*)&Xb[base] = o;
            return;
        }
        t -= X_N4;
        if (t < W1_N4)                 { src = W1;    dst = W1b;    off = t; }
        else if (t < W1_N4 + W2_N4)    { src = W2;    dst = W2b;    off = t - W1_N4; }
        else if (t < W1_N4 + W2_N4 + ER_N4) { src = emb_r; dst = emb_rb; off = t - W1_N4 - W2_N4; }
        else return;
    }
    const float4 v = *(const float4*)&src[off * 4];
    ushort4 o;
    o.x = f2bf(v.x); o.y = f2bf(v.y); o.z = f2bf(v.z); o.w = f2bf(v.w);
    *(ushort4*)&dst[off * 4] = o;
}

// bf16 MFMA GEMM, BK=64, double-buffered LDS (one barrier per k-step).
// C[m][n] = act(sum_k A[m][k]*Bw[n][k] + bias[n]); A [M][K], Bw [N][K] row-major bf16.
// Tile 64x64, 4 waves; output stride fixed = 512.
template<int K, bool RELU, bool OUT_BF16, bool BIAS, bool EMIT_RHALF>
__global__ __launch_bounds__(256) void gemm_bf16_kernel(
    const ushort* __restrict__ A, const ushort* __restrict__ Bw,
    const float* __restrict__ bias, ushort* __restrict__ outb,
    float* __restrict__ outf, ushort* __restrict__ rhalf)
{
    constexpr int PITCH = 72;                     // 64 + 8 pad (ushort units)
    __shared__ ushort Asl[2][64 * PITCH];
    __shared__ ushort Bsl[2][64 * PITCH];
    const int tid = threadIdx.x;
    const int lane = tid & 63, w = tid >> 6;
    const int n0 = blockIdx.x * 64, m0 = blockIdx.y * 64;
    const int lrow = tid >> 2, lcg = (tid & 3) * 16;  // 4 loaders/row x 32B
    const int q = lane >> 4, l16 = lane & 15;

    const ushort* aptr = &A[(size_t)(m0 + lrow) * K + lcg];
    const ushort* bptr = &Bw[(size_t)(n0 + lrow) * K + lcg];

    short8 ra0 = *(const short8*)aptr;
    short8 ra1 = *(const short8*)(aptr + 8);
    short8 rb0 = *(const short8*)bptr;
    short8 rb1 = *(const short8*)(bptr + 8);
    *(short8*)&Asl[0][lrow * PITCH + lcg]     = ra0;
    *(short8*)&Asl[0][lrow * PITCH + lcg + 8] = ra1;
    *(short8*)&Bsl[0][lrow * PITCH + lcg]     = rb0;
    *(short8*)&Bsl[0][lrow * PITCH + lcg + 8] = rb1;

    float4v acc[4] = {};
    int buf = 0;
    __syncthreads();
    for (int k0 = 0; k0 < K; k0 += 64) {
        if (k0 + 64 < K) {                        // prefetch next tile into regs
            ra0 = *(const short8*)(aptr + k0 + 64);
            ra1 = *(const short8*)(aptr + k0 + 64 + 8);
            rb0 = *(const short8*)(bptr + k0 + 64);
            rb1 = *(const short8*)(bptr + k0 + 64 + 8);
        }
        #pragma unroll
        for (int kh = 0; kh < 64; kh += 32) {
            const short8 af = *(const short8*)&Asl[buf][(w * 16 + l16) * PITCH + kh + q * 8];
            #pragma unroll
            for (int jn = 0; jn < 4; ++jn) {
                const short8 bfr = *(const short8*)&Bsl[buf][(jn * 16 + l16) * PITCH + kh + q * 8];
                acc[jn] = __builtin_amdgcn_mfma_f32_16x16x32_bf16(af, bfr, acc[jn], 0, 0, 0);
            }
        }
        if (k0 + 64 < K) {
            *(short8*)&Asl[buf ^ 1][lrow * PITCH + lcg]     = ra0;
            *(short8*)&Asl[buf ^ 1][lrow * PITCH + lcg + 8] = ra1;
            *(short8*)&Bsl[buf ^ 1][lrow * PITCH + lcg]     = rb0;
            *(short8*)&Bsl[buf ^ 1][lrow * PITCH + lcg + 8] = rb1;
            __syncthreads();
            buf ^= 1;
        }
    }
    #pragma unroll
    for (int jn = 0; jn < 4; ++jn) {
        const int n = n0 + jn * 16 + l16;
        const float bn = BIAS ? bias[n] : 0.0f;
        #pragma unroll
        for (int r = 0; r < 4; ++r) {
            const int m = m0 + w * 16 + q * 4 + r;
            float c = acc[jn][r] + bn;
            if (RELU) c = fmaxf(c, 0.0f);
            if (OUT_BF16) outb[(size_t)m * AD_ + n] = f2bf(c);
            else if (!EMIT_RHALF || n >= 256) outf[(size_t)m * AD_ + n] = c;
            if (EMIT_RHALF && n < 256) rhalf[(size_t)m * 256 + n] = f2bf(c);
        }
    }
}

// scores + masked softmax + entropy. One block per batch row, 4 waves.
// emb_r part precomputed in R[b][r]; emb_e gathered as bf16, TWO rows per
// wave-load (lanes 0-31 row k, 32-63 row k+1), width-32 reduce.
// Masked-out rows are REDIRECTED to row 0 (index 0): keeps the 8-load
// straight-line pipeline (no branches, full MLP) while all dead gathers hit
// the same 4 L1-hot lines; the -1e31 bias zeroes their softmax weight.
__global__ __launch_bounds__(256) void scores_kernel(
    const float* __restrict__ X2, const float* __restrict__ R,
    const ushort* __restrict__ emb_eb, const float* __restrict__ mask,
    const int* __restrict__ r_space, const int* __restrict__ e_space,
    float* __restrict__ dist, float* __restrict__ entropy)
{
    const int b = blockIdx.x;
    const int tid = threadIdx.x;
    const int lane = tid & 63, wid = tid >> 6;
    const int half = lane >> 5, l32 = lane & 31;

    __shared__ int   s_e[K_];
    __shared__ float s_dot[K_];
    __shared__ float s_red[12];

    // phase A: fully parallel per-thread (k == tid) bias precompute
    const int   e_mine = e_space[b * K_ + tid];
    const int   r_mine = r_space[b * K_ + tid];
    const float mk     = mask[b * K_ + tid];
    s_e[tid] = (mk != 0.0f) ? e_mine : 0;      // dead gathers -> row 0 (L1-hot)
    const float bias   = R[(size_t)b * NRP_ + r_mine] - (1.0f - mk) * 1e31f;
    const float4 x0 = *(const float4*)&X2[(size_t)b * AD_ + 256 + l32 * 8];
    const float4 x1 = *(const float4*)&X2[(size_t)b * AD_ + 256 + l32 * 8 + 4];
    __syncthreads();

    // phase B: wave wid handles k in [wid*64, wid*64+64); 8 loads (16 rows) in flight
    const int kbase = wid * 64;
    #pragma unroll
    for (int kk = 0; kk < 64; kk += 16) {
        float p[8];
        #pragma unroll
        for (int u = 0; u < 8; ++u) {
            const int row = kbase + kk + u * 2 + half;
            const int e = s_e[row];
            const short8 ae = *(const short8*)&emb_eb[(size_t)e * 256 + l32 * 8];
            p[u] = bf2f(ae[0]) * x0.x + bf2f(ae[1]) * x0.y
                 + bf2f(ae[2]) * x0.z + bf2f(ae[3]) * x0.w
                 + bf2f(ae[4]) * x1.x + bf2f(ae[5]) * x1.y
                 + bf2f(ae[6]) * x1.z + bf2f(ae[7]) * x1.w;
        }
        #pragma unroll
        for (int off = 16; off >= 1; off >>= 1) {
            #pragma unroll
            for (int u = 0; u < 8; ++u) p[u] += __shfl_down(p[u], off, 32);
        }
        if (l32 == 0) {
            #pragma unroll
            for (int u = 0; u < 8; ++u) s_dot[kbase + kk + u * 2 + half] = p[u];
        }
    }
    __syncthreads();

    const float v = s_dot[tid] + bias;

    // block max
    float m = v;
    #pragma unroll
    for (int off = 32; off >= 1; off >>= 1) m = fmaxf(m, __shfl_down(m, off));
    if (lane == 0) s_red[wid] = m;
    __syncthreads();
    if (tid == 0)
        s_red[8] = fmaxf(fmaxf(s_red[0], s_red[1]), fmaxf(s_red[2], s_red[3]));
    __syncthreads();
    const float bmax = s_red[8];

    // joint block sum of ev and ev*(v-bmax)
    const float ev = __expf(v - bmax);       // masked: exp(-1e31)=0
    float s = ev;
    float t = ev * (v - bmax);               // masked: 0 * finite = 0
    #pragma unroll
    for (int off = 32; off >= 1; off >>= 1) {
        s += __shfl_down(s, off);
        t += __shfl_down(t, off);
    }
    if (lane == 0) { s_red[wid] = s; s_red[4 + wid] = t; }
    __syncthreads();
    if (tid == 0) {
        s_red[9]  = s_red[0] + s_red[1] + s_red[2] + s_red[3];
        s_red[10] = s_red[4] + s_red[5] + s_red[6] + s_red[7];
    }
    __syncthreads();
    const float ssum = s_red[9];

    dist[(size_t)b * K_ + tid] = ev / ssum;
    if (tid == 0)
        entropy[b] = logf(ssum) - s_red[10] / ssum;   // = -sum p log p
}

extern "C" void kernel_launch(void* const* d_in, const int* in_sizes, int n_in,
                              void* d_out, int out_size, void* d_ws, size_t ws_size,
                              hipStream_t stream) {
    const float* E     = (const float*)d_in[0];
    const float* H     = (const float*)d_in[1];
    const float* Q     = (const float*)d_in[2];
    const float* W1    = (const float*)d_in[3];
    const float* b1    = (const float*)d_in[4];
    const float* W2    = (const float*)d_in[5];
    const float* b2    = (const float*)d_in[6];
    const float* emb_r = (const float*)d_in[7];
    const float* emb_e = (const float*)d_in[8];
    const float* mask  = (const float*)d_in[9];
    const int* r_space = (const int*)d_in[10];
    const int* e_space = (const int*)d_in[11];

    float* out_dist = (float*)d_out;
    float* out_ent  = out_dist + (size_t)B_ * K_;

    char* ws = (char*)d_ws;
    ushort* Xb     = (ushort*)ws;  ws += (size_t)B_ * IN_ * 2;     //  3.00 MB
    ushort* W1b    = (ushort*)ws;  ws += (size_t)AD_ * IN_ * 2;    //  0.75 MB
    ushort* W2b    = (ushort*)ws;  ws += (size_t)AD_ * AD_ * 2;    //  0.50 MB
    ushort* emb_rb = (ushort*)ws;  ws += (size_t)NRP_ * 256 * 2;   //  0.25 MB (rows 500-511 poison, unread)
    ushort* emb_eb = (ushort*)ws;  ws += (size_t)NE_ * 256 * 2;    // 51.20 MB
    ushort* H1b    = (ushort*)ws;  ws += (size_t)B_ * AD_ * 2;     //  2.00 MB
    float*  X2     = (float*)ws;   ws += (size_t)B_ * AD_ * 4;     //  4.00 MB (n<256 left poisoned, unread)
    ushort* X2rb   = (ushort*)ws;  ws += (size_t)B_ * 256 * 2;     //  1.00 MB
    float*  Rt     = (float*)ws;   ws += (size_t)B_ * NRP_ * 4;    //  4.00 MB

    prep_kernel<<<(PREP_TOTAL + 255) / 256, 256, 0, stream>>>(
        E, H, Q, W1, W2, emb_r, emb_e, Xb, W1b, W2b, emb_rb, emb_eb);

    dim3 g(AD_ / 64, B_ / 64);   // (8, 32)
    gemm_bf16_kernel<IN_, true,  true,  true,  false><<<g, 256, 0, stream>>>(
        Xb, W1b, b1, H1b, nullptr, nullptr);
    gemm_bf16_kernel<AD_, false, false, true,  true ><<<g, 256, 0, stream>>>(
        H1b, W2b, b2, nullptr, X2, X2rb);
    // R = X2[:, :256] @ emb_r^T  -> [B, 512pad] f32
    gemm_bf16_kernel<256, false, false, false, false><<<dim3(NRP_ / 64, B_ / 64), 256, 0, stream>>>(
        X2rb, emb_rb, nullptr, nullptr, Rt, nullptr);

    scores_kernel<<<B_, 256, 0, stream>>>(X2, Rt, emb_eb, mask,
                                          r_space, e_space, out_dist, out_ent);
}

// Round 9
// 220.114 us; speedup vs baseline: 1.1771x; 1.0789x over previous
//
#include <hip/hip_runtime.h>
#include <hip/hip_bf16.h>
#include <hip/hip_fp8.h>
#include <math.h>

#define B_   2048
#define K_   256
#define AD_  512
#define IN_  768
#define NR_  500
#define NRP_ 512   // padded
#define NE_  100000

typedef __attribute__((ext_vector_type(8))) short short8;
typedef __attribute__((ext_vector_type(4))) float float4v;

__device__ __forceinline__ unsigned short f2bf(float f) {
    unsigned int u = __float_as_uint(f);
    unsigned int r = u + 0x7FFF + ((u >> 16) & 1);   // round-to-nearest-even
    return (unsigned short)(r >> 16);
}
__device__ __forceinline__ float bf2f(short s) {
    return __uint_as_float(((unsigned int)(unsigned short)s) << 16);
}
__device__ __forceinline__ unsigned char f2fp8(float f) {
    __hip_fp8_e4m3 t(f);                             // OCP e4m3, HW cvt on gfx950
    return (unsigned char)t.__x;
}
__device__ __forceinline__ float fp8tof(unsigned int byte) {
    __hip_fp8_e4m3 t; t.__x = (__hip_fp8_storage_t)byte; return (float)t;
}
__device__ __forceinline__ float dot4_fp8(unsigned int d, const float* x) {
    return fp8tof(d & 0xffu)         * x[0] + fp8tof((d >> 8) & 0xffu)  * x[1]
         + fp8tof((d >> 16) & 0xffu) * x[2] + fp8tof(d >> 24)           * x[3];
}

// one prep kernel: emb_e->fp8 (bulk), cast concat [E|H|Q] -> Xb, W1/W2/emb_r -> bf16
#define EE_N4 (NE_ * 256 / 4)    // 6,400,000
#define X_N4  (B_ * IN_ / 4)     // 393,216
#define W1_N4 (AD_ * IN_ / 4)    // 98,304
#define W2_N4 (AD_ * AD_ / 4)    // 65,536
#define ER_N4 (NR_ * 256 / 4)    // 32,000
#define PREP_TOTAL (EE_N4 + X_N4 + W1_N4 + W2_N4 + ER_N4)
__global__ __launch_bounds__(256) void prep_kernel(
    const float* __restrict__ E, const float* __restrict__ H,
    const float* __restrict__ Q, const float* __restrict__ W1,
    const float* __restrict__ W2, const float* __restrict__ emb_r,
    const float* __restrict__ emb_e,
    ushort* __restrict__ Xb, ushort* __restrict__ W1b,
    ushort* __restrict__ W2b, ushort* __restrict__ emb_rb,
    unsigned char* __restrict__ emb_e8)
{
    int t = blockIdx.x * 256 + threadIdx.x;
    if (t < EE_N4) {                                  // fp8 encode, 4 elems/thread
        const float4 v = *(const float4*)&emb_e[(size_t)t * 4];
        uchar4 o;
        o.x = f2fp8(v.x); o.y = f2fp8(v.y); o.z = f2fp8(v.z); o.w = f2fp8(v.w);
        *(uchar4*)&emb_e8[(size_t)t * 4] = o;
        return;
    }
    t -= EE_N4;
    const float* src; ushort* dst; long off;
    if (t < X_N4) {
        const int base = t * 4;
        const int row = base / IN_, col = base % IN_;
        src = (col < 256) ? &E[row * 256 + col]
            : (col < 512) ? &H[row * 256 + col - 256]
                          : &Q[row * 256 + col - 512];
        const float4 v = *(const float4*)src;
        ushort4 o;
        o.x = f2bf(v.x); o.y = f2bf(v.y); o.z = f2bf(v.z); o.w = f2bf(v.w);
        *(ushort4*)&Xb[base] = o;
        return;
    }
    t -= X_N4;
    if (t < W1_N4)                 { src = W1;    dst = W1b;    off = t; }
    else if (t < W1_N4 + W2_N4)    { src = W2;    dst = W2b;    off = t - W1_N4; }
    else if (t < W1_N4 + W2_N4 + ER_N4) { src = emb_r; dst = emb_rb; off = t - W1_N4 - W2_N4; }
    else return;
    const float4 v = *(const float4*)&src[off * 4];
    ushort4 o;
    o.x = f2bf(v.x); o.y = f2bf(v.y); o.z = f2bf(v.z); o.w = f2bf(v.w);
    *(ushort4*)&dst[off * 4] = o;
}

// bf16 MFMA GEMM, BK=64, double-buffered LDS (one barrier per k-step).
// C[m][n] = act(sum_k A[m][k]*Bw[n][k] + bias[n]); A [M][K], Bw [N][K] row-major bf16.
// Tile 64x64, 4 waves; output stride fixed = 512.
template<int K, bool RELU, bool OUT_BF16, bool BIAS, bool EMIT_RHALF>
__global__ __launch_bounds__(256) void gemm_bf16_kernel(
    const ushort* __restrict__ A, const ushort* __restrict__ Bw,
    const float* __restrict__ bias, ushort* __restrict__ outb,
    float* __restrict__ outf, ushort* __restrict__ rhalf)
{
    constexpr int PITCH = 72;                     // 64 + 8 pad (ushort units)
    __shared__ ushort Asl[2][64 * PITCH];
    __shared__ ushort Bsl[2][64 * PITCH];
    const int tid = threadIdx.x;
    const int lane = tid & 63, w = tid >> 6;
    const int n0 = blockIdx.x * 64, m0 = blockIdx.y * 64;
    const int lrow = tid >> 2, lcg = (tid & 3) * 16;  // 4 loaders/row x 32B
    const int q = lane >> 4, l16 = lane & 15;

    const ushort* aptr = &A[(size_t)(m0 + lrow) * K + lcg];
    const ushort* bptr = &Bw[(size_t)(n0 + lrow) * K + lcg];

    short8 ra0 = *(const short8*)aptr;
    short8 ra1 = *(const short8*)(aptr + 8);
    short8 rb0 = *(const short8*)bptr;
    short8 rb1 = *(const short8*)(bptr + 8);
    *(short8*)&Asl[0][lrow * PITCH + lcg]     = ra0;
    *(short8*)&Asl[0][lrow * PITCH + lcg + 8] = ra1;
    *(short8*)&Bsl[0][lrow * PITCH + lcg]     = rb0;
    *(short8*)&Bsl[0][lrow * PITCH + lcg + 8] = rb1;

    float4v acc[4] = {};
    int buf = 0;
    __syncthreads();
    for (int k0 = 0; k0 < K; k0 += 64) {
        if (k0 + 64 < K) {                        // prefetch next tile into regs
            ra0 = *(const short8*)(aptr + k0 + 64);
            ra1 = *(const short8*)(aptr + k0 + 64 + 8);
            rb0 = *(const short8*)(bptr + k0 + 64);
            rb1 = *(const short8*)(bptr + k0 + 64 + 8);
        }
        #pragma unroll
        for (int kh = 0; kh < 64; kh += 32) {
            const short8 af = *(const short8*)&Asl[buf][(w * 16 + l16) * PITCH + kh + q * 8];
            #pragma unroll
            for (int jn = 0; jn < 4; ++jn) {
                const short8 bfr = *(const short8*)&Bsl[buf][(jn * 16 + l16) * PITCH + kh + q * 8];
                acc[jn] = __builtin_amdgcn_mfma_f32_16x16x32_bf16(af, bfr, acc[jn], 0, 0, 0);
            }
        }
        if (k0 + 64 < K) {
            *(short8*)&Asl[buf ^ 1][lrow * PITCH + lcg]     = ra0;
            *(short8*)&Asl[buf ^ 1][lrow * PITCH + lcg + 8] = ra1;
            *(short8*)&Bsl[buf ^ 1][lrow * PITCH + lcg]     = rb0;
            *(short8*)&Bsl[buf ^ 1][lrow * PITCH + lcg + 8] = rb1;
            __syncthreads();
            buf ^= 1;
        }
    }
    #pragma unroll
    for (int jn = 0; jn < 4; ++jn) {
        const int n = n0 + jn * 16 + l16;
        const float bn = BIAS ? bias[n] : 0.0f;
        #pragma unroll
        for (int r = 0; r < 4; ++r) {
            const int m = m0 + w * 16 + q * 4 + r;
            float c = acc[jn][r] + bn;
            if (RELU) c = fmaxf(c, 0.0f);
            if (OUT_BF16) outb[(size_t)m * AD_ + n] = f2bf(c);
            else if (!EMIT_RHALF || n >= 256) outf[(size_t)m * AD_ + n] = c;
            if (EMIT_RHALF && n < 256) rhalf[(size_t)m * 256 + n] = f2bf(c);
        }
    }
}

// scores + masked softmax + entropy. One block per batch row, 4 waves.
// emb_r part precomputed in R[b][r]; emb_e gathered as fp8 e4m3: one 16B/lane
// wave-load covers FOUR rows (16 lanes/row), width-16 reduce. 8 loads in
// flight (32 rows), 2 iterations per wave. Masked-out rows redirect to row 0
// (L1-hot); their -1e31 bias zeroes the softmax weight.
__global__ __launch_bounds__(256) void scores_kernel(
    const float* __restrict__ X2, const float* __restrict__ R,
    const unsigned char* __restrict__ emb_e8, const float* __restrict__ mask,
    const int* __restrict__ r_space, const int* __restrict__ e_space,
    float* __restrict__ dist, float* __restrict__ entropy)
{
    const int b = blockIdx.x;
    const int tid = threadIdx.x;
    const int lane = tid & 63, wid = tid >> 6;
    const int l16 = lane & 15, q4 = lane >> 4;   // row-span lane, row-quarter

    __shared__ int   s_e[K_];
    __shared__ float s_dot[K_];
    __shared__ float s_red[12];

    // phase A: fully parallel per-thread (k == tid) bias precompute
    const int   e_mine = e_space[b * K_ + tid];
    const int   r_mine = r_space[b * K_ + tid];
    const float mk     = mask[b * K_ + tid];
    s_e[tid] = (mk != 0.0f) ? e_mine : 0;        // dead gathers -> row 0 (L1-hot)
    const float bias   = R[(size_t)b * NRP_ + r_mine] - (1.0f - mk) * 1e31f;
    // xe: 16 dims per lane (dims [l16*16, l16*16+16) of X2e)
    float x[16];
    #pragma unroll
    for (int i = 0; i < 4; ++i) {
        const float4 xv = *(const float4*)&X2[(size_t)b * AD_ + 256 + l16 * 16 + i * 4];
        x[i * 4 + 0] = xv.x; x[i * 4 + 1] = xv.y;
        x[i * 4 + 2] = xv.z; x[i * 4 + 3] = xv.w;
    }
    __syncthreads();

    // phase B: wave wid handles k in [wid*64, wid*64+64); 8 loads (32 rows) in flight
    const int kbase = wid * 64;
    #pragma unroll
    for (int it = 0; it < 2; ++it) {
        uint4 wv[8];
        #pragma unroll
        for (int u = 0; u < 8; ++u) {
            const int row = kbase + it * 32 + u * 4 + q4;
            const int e = s_e[row];
            wv[u] = *(const uint4*)&emb_e8[(size_t)e * 256 + l16 * 16];
        }
        float p[8];
        #pragma unroll
        for (int u = 0; u < 8; ++u) {
            p[u] = dot4_fp8(wv[u].x, &x[0]) + dot4_fp8(wv[u].y, &x[4])
                 + dot4_fp8(wv[u].z, &x[8]) + dot4_fp8(wv[u].w, &x[12]);
        }
        #pragma unroll
        for (int off = 8; off >= 1; off >>= 1) {
            #pragma unroll
            for (int u = 0; u < 8; ++u) p[u] += __shfl_down(p[u], off, 16);
        }
        if (l16 == 0) {
            #pragma unroll
            for (int u = 0; u < 8; ++u) s_dot[kbase + it * 32 + u * 4 + q4] = p[u];
        }
    }
    __syncthreads();

    const float v = s_dot[tid] + bias;

    // block max
    float m = v;
    #pragma unroll
    for (int off = 32; off >= 1; off >>= 1) m = fmaxf(m, __shfl_down(m, off));
    if (lane == 0) s_red[wid] = m;
    __syncthreads();
    if (tid == 0)
        s_red[8] = fmaxf(fmaxf(s_red[0], s_red[1]), fmaxf(s_red[2], s_red[3]));
    __syncthreads();
    const float bmax = s_red[8];

    // joint block sum of ev and ev*(v-bmax)
    const float ev = __expf(v - bmax);       // masked: exp(-1e31)=0
    float s = ev;
    float t = ev * (v - bmax);               // masked: 0 * finite = 0
    #pragma unroll
    for (int off = 32; off >= 1; off >>= 1) {
        s += __shfl_down(s, off);
        t += __shfl_down(t, off);
    }
    if (lane == 0) { s_red[wid] = s; s_red[4 + wid] = t; }
    __syncthreads();
    if (tid == 0) {
        s_red[9]  = s_red[0] + s_red[1] + s_red[2] + s_red[3];
        s_red[10] = s_red[4] + s_red[5] + s_red[6] + s_red[7];
    }
    __syncthreads();
    const float ssum = s_red[9];

    dist[(size_t)b * K_ + tid] = ev / ssum;
    if (tid == 0)
        entropy[b] = logf(ssum) - s_red[10] / ssum;   // = -sum p log p
}

extern "C" void kernel_launch(void* const* d_in, const int* in_sizes, int n_in,
                              void* d_out, int out_size, void* d_ws, size_t ws_size,
                              hipStream_t stream) {
    const float* E     = (const float*)d_in[0];
    const float* H     = (const float*)d_in[1];
    const float* Q     = (const float*)d_in[2];
    const float* W1    = (const float*)d_in[3];
    const float* b1    = (const float*)d_in[4];
    const float* W2    = (const float*)d_in[5];
    const float* b2    = (const float*)d_in[6];
    const float* emb_r = (const float*)d_in[7];
    const float* emb_e = (const float*)d_in[8];
    const float* mask  = (const float*)d_in[9];
    const int* r_space = (const int*)d_in[10];
    const int* e_space = (const int*)d_in[11];

    float* out_dist = (float*)d_out;
    float* out_ent  = out_dist + (size_t)B_ * K_;

    char* ws = (char*)d_ws;
    ushort* Xb     = (ushort*)ws;         ws += (size_t)B_ * IN_ * 2;    //  3.00 MB
    ushort* W1b    = (ushort*)ws;         ws += (size_t)AD_ * IN_ * 2;   //  0.75 MB
    ushort* W2b    = (ushort*)ws;         ws += (size_t)AD_ * AD_ * 2;   //  0.50 MB
    ushort* emb_rb = (ushort*)ws;         ws += (size_t)NRP_ * 256 * 2;  //  0.25 MB (rows 500-511 poison, unread)
    unsigned char* emb_e8 = (unsigned char*)ws; ws += (size_t)NE_ * 256; // 25.60 MB
    ushort* H1b    = (ushort*)ws;         ws += (size_t)B_ * AD_ * 2;    //  2.00 MB
    float*  X2     = (float*)ws;          ws += (size_t)B_ * AD_ * 4;    //  4.00 MB (n<256 left poisoned, unread)
    ushort* X2rb   = (ushort*)ws;         ws += (size_t)B_ * 256 * 2;    //  1.00 MB
    float*  Rt     = (float*)ws;          ws += (size_t)B_ * NRP_ * 4;   //  4.00 MB

    prep_kernel<<<(PREP_TOTAL + 255) / 256, 256, 0, stream>>>(
        E, H, Q, W1, W2, emb_r, emb_e, Xb, W1b, W2b, emb_rb, emb_e8);

    dim3 g(AD_ / 64, B_ / 64);   // (8, 32)
    gemm_bf16_kernel<IN_, true,  true,  true,  false><<<g, 256, 0, stream>>>(
        Xb, W1b, b1, H1b, nullptr, nullptr);
    gemm_bf16_kernel<AD_, false, false, true,  true ><<<g, 256, 0, stream>>>(
        H1b, W2b, b2, nullptr, X2, X2rb);
    // R = X2[:, :256] @ emb_r^T  -> [B, 512pad] f32
    gemm_bf16_kernel<256, false, false, false, false><<<dim3(NRP_ / 64, B_ / 64), 256, 0, stream>>>(
        X2rb, emb_rb, nullptr, nullptr, Rt, nullptr);

    scores_kernel<<<B_, 256, 0, stream>>>(X2, Rt, emb_e8, mask,
                                          r_space, e_space, out_dist, out_ent);
}